// Round 5
// baseline (1095.985 us; speedup 1.0000x reference)
//
#include <hip/hip_runtime.h>

#define BN_EPS 1e-5f

// ---------------------------------------------------------------------------
// conv1x1: out[b,co,p] = epilogue( sum_ci w[co,ci] * x[b,ci,p] )
// Compile-time C_IN; CO=8 co per block; PIX pixels/thread; weights in LDS.
// MODE 0: + bias (p0)      MODE 1: BN(g=p0, bt=p1, m=p2, v=p3) + ReLU
// grid: (ceil(HW/(256*PIX)), 8, B), block 256.  Requires HW % PIX == 0.
// ---------------------------------------------------------------------------
template<int C_IN, int PIX, int MODE>
__global__ __launch_bounds__(256)
void conv1x1_kernel(const float* __restrict__ x, const float* __restrict__ w,
                    const float* __restrict__ p0, const float* __restrict__ p1,
                    const float* __restrict__ p2, const float* __restrict__ p3,
                    float* __restrict__ out, int HW)
{
    constexpr int CO = 8;
    __shared__ float wl[C_IN][CO];

    int tid = threadIdx.x;
    int co0 = blockIdx.y * CO;
    int b   = blockIdx.z;

    for (int i = tid; i < C_IN * CO; i += 256) {
        int ci = i >> 3, j = i & 7;
        wl[ci][j] = w[(co0 + j) * C_IN + ci];
    }
    __syncthreads();

    int p = (blockIdx.x * 256 + tid) * PIX;
    if (p >= HW) return;

    float acc[CO][PIX];
#pragma unroll
    for (int j = 0; j < CO; ++j)
#pragma unroll
        for (int q = 0; q < PIX; ++q) acc[j][q] = 0.f;

    const float* xp = x + (size_t)b * C_IN * HW + p;

#pragma unroll 8
    for (int ci = 0; ci < C_IN; ++ci) {
        float xv[PIX];
        if (PIX == 4) {
            float4 v = *(const float4*)(xp + (size_t)ci * HW);
            xv[0] = v.x; xv[1] = v.y; xv[2] = v.z; xv[3] = v.w;
        } else if (PIX == 2) {
            float2 v = *(const float2*)(xp + (size_t)ci * HW);
            xv[0] = v.x; xv[1] = v.y;
        } else {
            xv[0] = xp[(size_t)ci * HW];
        }
        float4 wa = *(const float4*)&wl[ci][0];
        float4 wb = *(const float4*)&wl[ci][4];
        float wj[CO] = {wa.x, wa.y, wa.z, wa.w, wb.x, wb.y, wb.z, wb.w};
#pragma unroll
        for (int j = 0; j < CO; ++j)
#pragma unroll
            for (int q = 0; q < PIX; ++q)
                acc[j][q] = fmaf(wj[j], xv[q], acc[j][q]);
    }

    int C_out = gridDim.y * CO;
    float* op = out + ((size_t)(b * C_out + co0)) * HW + p;
#pragma unroll
    for (int j = 0; j < CO; ++j) {
        float scale, shift;
        if (MODE == 0) {
            scale = 1.f; shift = p0[co0 + j];
        } else {
            float inv = p0[co0 + j] * rsqrtf(p3[co0 + j] + BN_EPS);
            scale = inv; shift = p1[co0 + j] - p2[co0 + j] * inv;
        }
        float r[PIX];
#pragma unroll
        for (int q = 0; q < PIX; ++q) {
            r[q] = acc[j][q] * scale + shift;
            if (MODE == 1) r[q] = fmaxf(r[q], 0.f);
        }
        float* od = op + (size_t)j * HW;
        if (PIX == 4)      *(float4*)od = make_float4(r[0], r[1], r[2], r[3]);
        else if (PIX == 2) *(float2*)od = make_float2(r[0], r[1]);
        else               od[0] = r[0];
    }
}

// ---------------------------------------------------------------------------
// conv3x3 v4, pad=1, C_in=64.
// v3 was 48% VALUBusy: staging serialized behind barriers, CO=8 -> low
// FMA:LDS-read ratio. v4: CO_CHUNK=16/20 (2x FMA per LDS read, half the
// redundant fetch) + register-prefetch double buffer: chunk k+1's global
// loads are in flight during chunk k's compute (~4600 cyc >> 900 cyc HBM).
// LDS row stride 24 (2-way bank aliasing only = free).
// MODE 0: + bias (p0)      MODE 1: BN(g,bt,m,v)
// grid: (ceil(W/16), ceil(H/16), B * n_chunks), block 256 (16x16 tile)
// ---------------------------------------------------------------------------
template<int CO_CHUNK, int MODE>
__global__ __launch_bounds__(256)
void conv3x3_kernel(const float* __restrict__ x, const float* __restrict__ w,
                    const float* __restrict__ p0, const float* __restrict__ p1,
                    const float* __restrict__ p2, const float* __restrict__ p3,
                    float* __restrict__ out, int H, int W, int n_chunks)
{
    constexpr int CIN = 64, CI_CHUNK = 16, RS = 24;
    constexpr int NELEM = CI_CHUNK * 18 * 18;        // 5184
    constexpr int NLOAD = (NELEM + 255) / 256;       // 21 (v=20: only tid<64)
    __shared__ float lds[CI_CHUNK][18][RS];

    int tid = threadIdx.x;
    int lx = tid & 15, ly = tid >> 4;
    int x0 = blockIdx.x * 16, y0 = blockIdx.y * 16;
    int b     = blockIdx.z / n_chunks;
    int chunk = blockIdx.z % n_chunks;
    int co0   = chunk * CO_CHUNK;
    int gx = x0 + lx, gy = y0 + ly;

    float acc[CO_CHUNK];
#pragma unroll
    for (int j = 0; j < CO_CHUNK; ++j) acc[j] = 0.f;

    const float* xb = x + (size_t)b * CIN * H * W;

    float r[NLOAD];
    // prefetch chunk cc into registers (cc = base input channel)
#define PREFETCH(cc)                                                        \
    _Pragma("unroll")                                                       \
    for (int v = 0; v < NLOAD; ++v) {                                       \
        int i = tid + v * 256;                                              \
        if (v < NLOAD - 1 || i < NELEM) {                                   \
            int cl = i / 324;                                               \
            int rem = i - cl * 324;                                         \
            int rr = rem / 18, c = rem - rr * 18;                           \
            int yy = y0 + rr - 1, xx = x0 + c - 1;                          \
            bool ok = (yy >= 0) && (yy < H) && (xx >= 0) && (xx < W);       \
            r[v] = ok ? xb[((size_t)((cc) + cl) * H + yy) * W + xx] : 0.f;  \
        }                                                                   \
    }

    PREFETCH(0)

    for (int cc = 0; cc < CIN; cc += CI_CHUNK) {
        if (cc > 0) __syncthreads();    // previous compute done before overwrite
        // write prefetched registers to LDS
#pragma unroll
        for (int v = 0; v < NLOAD; ++v) {
            int i = tid + v * 256;
            if (v < NLOAD - 1 || i < NELEM) {
                int cl = i / 324;
                int rem = i - cl * 324;
                int rr = rem / 18, c = rem - rr * 18;
                lds[cl][rr][c] = r[v];
            }
        }
        __syncthreads();
        if (cc + CI_CHUNK < CIN) { PREFETCH(cc + CI_CHUNK) }

        for (int cl = 0; cl < CI_CHUNK; ++cl) {
            float iv[9];
#pragma unroll
            for (int dy = 0; dy < 3; ++dy)
#pragma unroll
                for (int dx = 0; dx < 3; ++dx)
                    iv[dy * 3 + dx] = lds[cl][ly + dy][lx + dx];

            const float* wp = w + ((size_t)co0 * CIN + (cc + cl)) * 9;
#pragma unroll
            for (int j = 0; j < CO_CHUNK; ++j) {
                const float* wj = wp + (size_t)j * CIN * 9;
#pragma unroll
                for (int t = 0; t < 9; ++t)
                    acc[j] = fmaf(wj[t], iv[t], acc[j]);
            }
        }
    }
#undef PREFETCH

    if (gx < W && gy < H) {
        int C_out = n_chunks * CO_CHUNK;
        float* op = out + ((size_t)(b * C_out + co0) * H + gy) * W + gx;
#pragma unroll
        for (int j = 0; j < CO_CHUNK; ++j) {
            float val;
            if (MODE == 0) {
                val = acc[j] + p0[co0 + j];
            } else {
                float inv = p0[co0 + j] * rsqrtf(p3[co0 + j] + BN_EPS);
                val = acc[j] * inv + (p1[co0 + j] - p2[co0 + j] * inv);
            }
            op[(size_t)j * H * W] = val;
        }
    }
}

// ---------------------------------------------------------------------------
// CARAFE v2: dst(b,64,2h,2w) += sum_k softmax_k(logits) * src[.., yh+i-2, xw+j-2]
// 25-bit validity mask, k-outer/channel-inner, channels split across blocks.
// grid: (ceil(2w/16), ceil(2h/16), B * (64/CPG))
// ---------------------------------------------------------------------------
template<int CPG>
__global__ __launch_bounds__(256, 4)
void carafe_kernel(const float* __restrict__ src, const float* __restrict__ logits,
                   float* __restrict__ dst, int h, int w)
{
    constexpr int NCG = 64 / CPG;
    int H = 2 * h, W = 2 * w;
    int x = blockIdx.x * 16 + (threadIdx.x & 15);
    int y = blockIdx.y * 16 + (threadIdx.x >> 4);
    int b  = blockIdx.z / NCG;
    int cg = blockIdx.z % NCG;
    if (x >= W || y >= H) return;

    int xw = x >> 1, yh = y >> 1;
    int par = (y & 1) * 2 + (x & 1);
    size_t hw = (size_t)h * w;

    const float* lp = logits + ((size_t)(b * 100 + par) * h + yh) * w + xw;
    float l[25];
    float mx = -1e30f;
#pragma unroll
    for (int k = 0; k < 25; ++k) {
        l[k] = lp[(size_t)(4 * k) * hw];
        mx = fmaxf(mx, l[k]);
    }
    float s = 0.f;
#pragma unroll
    for (int k = 0; k < 25; ++k) {
        l[k] = __expf(l[k] - mx);
        s += l[k];
    }
    float invs = 1.f / s;

    unsigned vmask = 0;
#pragma unroll
    for (int k = 0; k < 25; ++k) {
        int i = k / 5 - 2, j = k % 5 - 2;
        bool valid = (yh + i >= 0) && (yh + i < h) && (xw + j >= 0) && (xw + j < w);
        if (valid) vmask |= (1u << k);
        l[k] = valid ? l[k] * invs : 0.f;
    }

    int off0 = yh * w + xw;
    const float* sp = src + ((size_t)(b * 64 + cg * CPG)) * hw;

    float acc[CPG];
#pragma unroll
    for (int c = 0; c < CPG; ++c) acc[c] = 0.f;

#pragma unroll
    for (int k = 0; k < 25; ++k) {
        int i = k / 5 - 2, j = k % 5 - 2;
        int cst = i * w + j;
        int offk = off0 + (((vmask >> k) & 1u) ? cst : 0);
        const float* spk = sp + offk;
        float wk = l[k];
#pragma unroll
        for (int c = 0; c < CPG; ++c)
            acc[c] = fmaf(wk, spk[(size_t)c * hw], acc[c]);
    }

    float* dp = dst + (((size_t)(b * 64 + cg * CPG)) * H + y) * W + x;
#pragma unroll
    for (int c = 0; c < CPG; ++c)
        dp[(size_t)c * H * W] += acc[c];
}

// ---------------------------------------------------------------------------
extern "C" void kernel_launch(void* const* d_in, const int* in_sizes, int n_in,
                              void* d_out, int out_size, void* d_ws, size_t ws_size,
                              hipStream_t stream)
{
    const float* x0      = (const float*)d_in[0];
    const float* lat0_w  = (const float*)d_in[1];
    const float* lat0_b  = (const float*)d_in[2];
    const float* fpn0_w  = (const float*)d_in[3];
    const float* fpn0_b  = (const float*)d_in[4];
    const float* x1      = (const float*)d_in[5];
    const float* lat1_w  = (const float*)d_in[6];
    const float* lat1_b  = (const float*)d_in[7];
    const float* fpn1_w  = (const float*)d_in[8];
    const float* fpn1_b  = (const float*)d_in[9];
    const float* x2      = (const float*)d_in[10];
    const float* lat2_w  = (const float*)d_in[11];
    const float* lat2_b  = (const float*)d_in[12];
    const float* fpn2_w  = (const float*)d_in[13];
    const float* fpn2_b  = (const float*)d_in[14];
    const float* u0_comp_w = (const float*)d_in[15];
    const float* u0_enc_w  = (const float*)d_in[16];
    const float* u0_comp_g  = (const float*)d_in[17];
    const float* u0_comp_bt = (const float*)d_in[18];
    const float* u0_comp_m  = (const float*)d_in[19];
    const float* u0_comp_v  = (const float*)d_in[20];
    const float* u0_enc_g   = (const float*)d_in[21];
    const float* u0_enc_bt  = (const float*)d_in[22];
    const float* u0_enc_m   = (const float*)d_in[23];
    const float* u0_enc_v   = (const float*)d_in[24];
    const float* u1_comp_w = (const float*)d_in[25];
    const float* u1_enc_w  = (const float*)d_in[26];
    const float* u1_comp_g  = (const float*)d_in[27];
    const float* u1_comp_bt = (const float*)d_in[28];
    const float* u1_comp_m  = (const float*)d_in[29];
    const float* u1_comp_v  = (const float*)d_in[30];
    const float* u1_enc_g   = (const float*)d_in[31];
    const float* u1_enc_bt  = (const float*)d_in[32];
    const float* u1_enc_m   = (const float*)d_in[33];
    const float* u1_enc_v   = (const float*)d_in[34];

    float* out = (float*)d_out;
    const size_t OUT0 = 4ull * 64 * 96 * 160;   // 3,932,160
    const size_t OUT1 = 4ull * 64 * 48 * 80;    //   983,040
    float* out0 = out;
    float* out1 = out + OUT0;
    float* out2 = out + OUT0 + OUT1;

    float* lat0 = (float*)d_ws;
    float* lat1 = lat0 + OUT0;
    float* lat2 = lat1 + OUT1;
    // comp/enc scratch lives in the out0 region (overwritten last by fpn0 conv)
    float* comp = out0;
    float* enc  = out0 + OUT1;

    dim3 blk(256);

    // 1) lateral 1x1 convs + bias
    conv1x1_kernel<128, 4, 0><<<dim3(15, 8, 4), blk, 0, stream>>>(
        x0, lat0_w, lat0_b, nullptr, nullptr, nullptr, lat0, 96 * 160);
    conv1x1_kernel<256, 2, 0><<<dim3(8, 8, 4), blk, 0, stream>>>(
        x1, lat1_w, lat1_b, nullptr, nullptr, nullptr, lat1, 48 * 80);
    conv1x1_kernel<512, 1, 0><<<dim3(4, 8, 4), blk, 0, stream>>>(
        x2, lat2_w, lat2_b, nullptr, nullptr, nullptr, lat2, 24 * 40);

    // 2) CARAFE u1: lat1 += carafe(lat2)
    conv1x1_kernel<64, 1, 1><<<dim3(4, 8, 4), blk, 0, stream>>>(
        lat2, u1_comp_w, u1_comp_g, u1_comp_bt, u1_comp_m, u1_comp_v, comp, 24 * 40);
    conv3x3_kernel<20, 1><<<dim3(3, 2, 20), blk, 0, stream>>>(
        comp, u1_enc_w, u1_enc_g, u1_enc_bt, u1_enc_m, u1_enc_v, enc, 24, 40, 5);
    carafe_kernel<16><<<dim3(5, 3, 16), blk, 0, stream>>>(lat2, enc, lat1, 24, 40);

    // 3) CARAFE u0: lat0 += carafe(lat1)
    conv1x1_kernel<64, 1, 1><<<dim3(15, 8, 4), blk, 0, stream>>>(
        lat1, u0_comp_w, u0_comp_g, u0_comp_bt, u0_comp_m, u0_comp_v, comp, 48 * 80);
    conv3x3_kernel<20, 1><<<dim3(5, 3, 20), blk, 0, stream>>>(
        comp, u0_enc_w, u0_enc_g, u0_enc_bt, u0_enc_m, u0_enc_v, enc, 48, 80, 5);
    carafe_kernel<16><<<dim3(10, 6, 16), blk, 0, stream>>>(lat1, enc, lat0, 48, 80);

    // 4) output 3x3 convs + bias  (fpn0 LAST — its region held comp/enc scratch)
    conv3x3_kernel<16, 0><<<dim3(5, 3, 16), blk, 0, stream>>>(
        lat1, fpn1_w, fpn1_b, nullptr, nullptr, nullptr, out1, 48, 80, 4);
    conv3x3_kernel<16, 0><<<dim3(3, 2, 16), blk, 0, stream>>>(
        lat2, fpn2_w, fpn2_b, nullptr, nullptr, nullptr, out2, 24, 40, 4);
    conv3x3_kernel<16, 0><<<dim3(10, 6, 16), blk, 0, stream>>>(
        lat0, fpn0_w, fpn0_b, nullptr, nullptr, nullptr, out0, 96, 160, 4);
}

// Round 6
// 622.841 us; speedup vs baseline: 1.7597x; 1.7597x over previous
//
#include <hip/hip_runtime.h>

#define BN_EPS 1e-5f

typedef __attribute__((ext_vector_type(8))) short bf16x8;
typedef __attribute__((ext_vector_type(4))) float f32x4;

__device__ __forceinline__ unsigned short f2bf(float f) {
    unsigned u = __float_as_uint(f);
    return (unsigned short)((u + 0x7fffu + ((u >> 16) & 1u)) >> 16);   // RNE
}

// ---------------------------------------------------------------------------
// Weight transform: w[co][ci][3][3] fp32 -> wt[tap][co_pad][ci] bf16 (zero pad)
// z: 0..2 fpn0/1/2 (co 64->64), 3..4 enc0/1 (co 100->112). grid (252, 5)
// ---------------------------------------------------------------------------
__global__ __launch_bounds__(256)
void wt_transform(const float* __restrict__ w0, const float* __restrict__ w1,
                  const float* __restrict__ w2, const float* __restrict__ w3,
                  const float* __restrict__ w4, unsigned short* __restrict__ dst)
{
    int z = blockIdx.y;
    int i = blockIdx.x * 256 + threadIdx.x;
    const float* src; unsigned short* d; int C_out, COP;
    if (z < 3) {
        COP = 64; C_out = 64;
        src = (z == 0) ? w0 : (z == 1 ? w1 : w2);
        d = dst + z * 36864;
        if (i >= 36864) return;
    } else {
        COP = 112; C_out = 100;
        src = (z == 3) ? w3 : w4;
        d = dst + 110592 + (z - 3) * 64512;
        if (i >= 64512) return;
    }
    int tap = i / (COP * 64);
    int rem = i - tap * (COP * 64);
    int co = rem >> 6, ci = rem & 63;
    float v = (co < C_out) ? src[((size_t)co * 64 + ci) * 9 + tap] : 0.f;
    d[i] = f2bf(v);
}

// ---------------------------------------------------------------------------
// conv3x3 via bf16 MFMA (16x16x32), pad=1, C_in=64, fp32 accumulate.
// Block = 16x16 spatial tile, all C_out. LDS: halo 18x18 px, pixel-major
// 8-ci granules (16B) -> ds_read_b128 B-fragments, 2-way bank alias (free).
// A (weights) from wt[tap][COP][ci] bf16, 18 frags in VGPRs per co-tile.
// Wave w computes rows {w, w+4} and {w+8, w+12} (dual-row for ILP).
// D layout: co = co0 + (lane>>4)*4 + reg, px col = lane&15 (m89/m91 verified).
// MODE 0: +bias(p0)   MODE 1: BN(g,bt,m,v)
// grid: (ceil(W/16), ceil(H/16), B), block 256
// ---------------------------------------------------------------------------
template<int COP, int MODE>
__global__ __launch_bounds__(256, 4)
void conv3x3_mfma(const float* __restrict__ x, const unsigned short* __restrict__ wt,
                  const float* __restrict__ p0, const float* __restrict__ p1,
                  const float* __restrict__ p2, const float* __restrict__ p3,
                  float* __restrict__ out, int H, int W, int C_out)
{
    constexpr int NP = 324;                      // 18*18 halo pixels
    __shared__ unsigned short xs[8 * NP * 8];    // [cg][p][8ci] bf16, 41472 B

    int tid  = threadIdx.x;
    int lane = tid & 63, wid = tid >> 6;
    int lrow = lane >> 4, lcol = lane & 15;      // lrow = quad
    int x0 = blockIdx.x * 16, y0 = blockIdx.y * 16;
    int b  = blockIdx.z;
    int HWp = H * W;
    const float* xb = x + (size_t)b * 64 * HWp;

    // ---- stage halo tile (fp32 global -> bf16 LDS, transposed to px-major) ----
    unsigned int* wsl = (unsigned int*)xs;
    for (int p = tid; p < NP; p += 256) {
        int py = p / 18, px = p - py * 18;
        int gy = y0 + py - 1, gx = x0 + px - 1;
        bool ok = (gy >= 0) && (gy < H) && (gx >= 0) && (gx < W);
        const float* gp = xb + (size_t)gy * W + gx;
#pragma unroll 4
        for (int cp = 0; cp < 32; ++cp) {        // ci pair
            float v0 = 0.f, v1 = 0.f;
            if (ok) {
                v0 = gp[(size_t)(2 * cp) * HWp];
                v1 = gp[(size_t)(2 * cp + 1) * HWp];
            }
            unsigned pk = ((unsigned)f2bf(v1) << 16) | (unsigned)f2bf(v0);
            wsl[((cp >> 2) * NP + p) * 4 + (cp & 3)] = pk;
        }
    }
    __syncthreads();

    bool colok = (x0 + lcol) < W;

    for (int ct = 0; ct < COP / 16; ++ct) {
        int co0 = ct * 16;

        // A fragments: 9 taps x 2 K-halves, 16B/lane from wt
        bf16x8 a[9][2];
        const unsigned short* wl = wt + ((size_t)co0 + lcol) * 64 + lrow * 8;
#pragma unroll
        for (int t = 0; t < 9; ++t)
#pragma unroll
            for (int kb = 0; kb < 2; ++kb)
                a[t][kb] = *(const bf16x8*)(wl + (size_t)t * COP * 64 + kb * 32);

        // epilogue scale/shift per reg (co = co0 + lrow*4 + reg)
        float sc[4], sh[4];
#pragma unroll
        for (int rg = 0; rg < 4; ++rg) {
            int co = co0 + lrow * 4 + rg;
            int cc = (co < C_out) ? co : 0;
            if (MODE == 0) { sc[rg] = 1.f; sh[rg] = p0[cc]; }
            else {
                float inv = p0[cc] * rsqrtf(p3[cc] + BN_EPS);
                sc[rg] = inv; sh[rg] = p1[cc] - p2[cc] * inv;
            }
        }

#pragma unroll
        for (int rr = 0; rr < 2; ++rr) {
            int r0 = wid + rr * 8;               // rows r0 and r0+4
            f32x4 acc0 = {0.f, 0.f, 0.f, 0.f};
            f32x4 acc1 = {0.f, 0.f, 0.f, 0.f};
#pragma unroll
            for (int t = 0; t < 9; ++t) {
                int dy = t / 3, dx = t - dy * 3;
#pragma unroll
                for (int kb = 0; kb < 2; ++kb) {
                    int g0 = (kb * 4 + lrow) * NP + (r0 + dy) * 18 + lcol + dx;
                    bf16x8 b0 = *(const bf16x8*)(xs + (size_t)g0 * 8);
                    acc0 = __builtin_amdgcn_mfma_f32_16x16x32_bf16(a[t][kb], b0, acc0, 0, 0, 0);
                    bf16x8 b1 = *(const bf16x8*)(xs + ((size_t)g0 + 4 * 18) * 8);
                    acc1 = __builtin_amdgcn_mfma_f32_16x16x32_bf16(a[t][kb], b1, acc1, 0, 0, 0);
                }
            }
            int yA = y0 + r0, yB = y0 + r0 + 4;
#pragma unroll
            for (int rg = 0; rg < 4; ++rg) {
                int co = co0 + lrow * 4 + rg;
                if (colok && co < C_out) {
                    float* oc = out + (((size_t)b * C_out + co) * H) * W + x0 + lcol;
                    if (yA < H) oc[(size_t)yA * W] = acc0[rg] * sc[rg] + sh[rg];
                    if (yB < H) oc[(size_t)yB * W] = acc1[rg] * sc[rg] + sh[rg];
                }
            }
        }
    }
}

// ---------------------------------------------------------------------------
// conv1x1 (R2 version — register-resident, known good)
// MODE 0: + bias (p0)      MODE 1: BN(g,bt,m,v) + ReLU
// grid: (ceil(HW/(256*PIX)), 8, B), block 256
// ---------------------------------------------------------------------------
template<int C_IN, int PIX, int MODE>
__global__ __launch_bounds__(256)
void conv1x1_kernel(const float* __restrict__ x, const float* __restrict__ w,
                    const float* __restrict__ p0, const float* __restrict__ p1,
                    const float* __restrict__ p2, const float* __restrict__ p3,
                    float* __restrict__ out, int HW)
{
    constexpr int CO = 8;
    __shared__ float wl[C_IN][CO];

    int tid = threadIdx.x;
    int co0 = blockIdx.y * CO;
    int b   = blockIdx.z;

    for (int i = tid; i < C_IN * CO; i += 256) {
        int ci = i >> 3, j = i & 7;
        wl[ci][j] = w[(co0 + j) * C_IN + ci];
    }
    __syncthreads();

    int p = (blockIdx.x * 256 + tid) * PIX;
    if (p >= HW) return;

    float acc[CO][PIX];
#pragma unroll
    for (int j = 0; j < CO; ++j)
#pragma unroll
        for (int q = 0; q < PIX; ++q) acc[j][q] = 0.f;

    const float* xp = x + (size_t)b * C_IN * HW + p;

#pragma unroll 8
    for (int ci = 0; ci < C_IN; ++ci) {
        float xv[PIX];
        if (PIX == 4) {
            float4 v = *(const float4*)(xp + (size_t)ci * HW);
            xv[0] = v.x; xv[1] = v.y; xv[2] = v.z; xv[3] = v.w;
        } else if (PIX == 2) {
            float2 v = *(const float2*)(xp + (size_t)ci * HW);
            xv[0] = v.x; xv[1] = v.y;
        } else {
            xv[0] = xp[(size_t)ci * HW];
        }
        float4 wa = *(const float4*)&wl[ci][0];
        float4 wb = *(const float4*)&wl[ci][4];
        float wj[CO] = {wa.x, wa.y, wa.z, wa.w, wb.x, wb.y, wb.z, wb.w};
#pragma unroll
        for (int j = 0; j < CO; ++j)
#pragma unroll
            for (int q = 0; q < PIX; ++q)
                acc[j][q] = fmaf(wj[j], xv[q], acc[j][q]);
    }

    int C_out = gridDim.y * CO;
    float* op = out + ((size_t)(b * C_out + co0)) * HW + p;
#pragma unroll
    for (int j = 0; j < CO; ++j) {
        float scale, shift;
        if (MODE == 0) {
            scale = 1.f; shift = p0[co0 + j];
        } else {
            float inv = p0[co0 + j] * rsqrtf(p3[co0 + j] + BN_EPS);
            scale = inv; shift = p1[co0 + j] - p2[co0 + j] * inv;
        }
        float r[PIX];
#pragma unroll
        for (int q = 0; q < PIX; ++q) {
            r[q] = acc[j][q] * scale + shift;
            if (MODE == 1) r[q] = fmaxf(r[q], 0.f);
        }
        float* od = op + (size_t)j * HW;
        if (PIX == 4)      *(float4*)od = make_float4(r[0], r[1], r[2], r[3]);
        else if (PIX == 2) *(float2*)od = make_float2(r[0], r[1]);
        else               od[0] = r[0];
    }
}

// ---------------------------------------------------------------------------
// CARAFE v2 (R3 version — known good)
// grid: (ceil(2w/16), ceil(2h/16), B * (64/CPG))
// ---------------------------------------------------------------------------
template<int CPG>
__global__ __launch_bounds__(256, 4)
void carafe_kernel(const float* __restrict__ src, const float* __restrict__ logits,
                   float* __restrict__ dst, int h, int w)
{
    constexpr int NCG = 64 / CPG;
    int H = 2 * h, W = 2 * w;
    int x = blockIdx.x * 16 + (threadIdx.x & 15);
    int y = blockIdx.y * 16 + (threadIdx.x >> 4);
    int b  = blockIdx.z / NCG;
    int cg = blockIdx.z % NCG;
    if (x >= W || y >= H) return;

    int xw = x >> 1, yh = y >> 1;
    int par = (y & 1) * 2 + (x & 1);
    size_t hw = (size_t)h * w;

    const float* lp = logits + ((size_t)(b * 100 + par) * h + yh) * w + xw;
    float l[25];
    float mx = -1e30f;
#pragma unroll
    for (int k = 0; k < 25; ++k) {
        l[k] = lp[(size_t)(4 * k) * hw];
        mx = fmaxf(mx, l[k]);
    }
    float s = 0.f;
#pragma unroll
    for (int k = 0; k < 25; ++k) {
        l[k] = __expf(l[k] - mx);
        s += l[k];
    }
    float invs = 1.f / s;

    unsigned vmask = 0;
#pragma unroll
    for (int k = 0; k < 25; ++k) {
        int i = k / 5 - 2, j = k % 5 - 2;
        bool valid = (yh + i >= 0) && (yh + i < h) && (xw + j >= 0) && (xw + j < w);
        if (valid) vmask |= (1u << k);
        l[k] = valid ? l[k] * invs : 0.f;
    }

    int off0 = yh * w + xw;
    const float* sp = src + ((size_t)(b * 64 + cg * CPG)) * hw;

    float acc[CPG];
#pragma unroll
    for (int c = 0; c < CPG; ++c) acc[c] = 0.f;

#pragma unroll
    for (int k = 0; k < 25; ++k) {
        int i = k / 5 - 2, j = k % 5 - 2;
        int cst = i * w + j;
        int offk = off0 + (((vmask >> k) & 1u) ? cst : 0);
        const float* spk = sp + offk;
        float wk = l[k];
#pragma unroll
        for (int c = 0; c < CPG; ++c)
            acc[c] = fmaf(wk, spk[(size_t)c * hw], acc[c]);
    }

    float* dp = dst + (((size_t)(b * 64 + cg * CPG)) * H + y) * W + x;
#pragma unroll
    for (int c = 0; c < CPG; ++c)
        dp[(size_t)c * H * W] += acc[c];
}

// ---------------------------------------------------------------------------
extern "C" void kernel_launch(void* const* d_in, const int* in_sizes, int n_in,
                              void* d_out, int out_size, void* d_ws, size_t ws_size,
                              hipStream_t stream)
{
    const float* x0      = (const float*)d_in[0];
    const float* lat0_w  = (const float*)d_in[1];
    const float* lat0_b  = (const float*)d_in[2];
    const float* fpn0_w  = (const float*)d_in[3];
    const float* fpn0_b  = (const float*)d_in[4];
    const float* x1      = (const float*)d_in[5];
    const float* lat1_w  = (const float*)d_in[6];
    const float* lat1_b  = (const float*)d_in[7];
    const float* fpn1_w  = (const float*)d_in[8];
    const float* fpn1_b  = (const float*)d_in[9];
    const float* x2      = (const float*)d_in[10];
    const float* lat2_w  = (const float*)d_in[11];
    const float* lat2_b  = (const float*)d_in[12];
    const float* fpn2_w  = (const float*)d_in[13];
    const float* fpn2_b  = (const float*)d_in[14];
    const float* u0_comp_w = (const float*)d_in[15];
    const float* u0_enc_w  = (const float*)d_in[16];
    const float* u0_comp_g  = (const float*)d_in[17];
    const float* u0_comp_bt = (const float*)d_in[18];
    const float* u0_comp_m  = (const float*)d_in[19];
    const float* u0_comp_v  = (const float*)d_in[20];
    const float* u0_enc_g   = (const float*)d_in[21];
    const float* u0_enc_bt  = (const float*)d_in[22];
    const float* u0_enc_m   = (const float*)d_in[23];
    const float* u0_enc_v   = (const float*)d_in[24];
    const float* u1_comp_w = (const float*)d_in[25];
    const float* u1_enc_w  = (const float*)d_in[26];
    const float* u1_comp_g  = (const float*)d_in[27];
    const float* u1_comp_bt = (const float*)d_in[28];
    const float* u1_comp_m  = (const float*)d_in[29];
    const float* u1_comp_v  = (const float*)d_in[30];
    const float* u1_enc_g   = (const float*)d_in[31];
    const float* u1_enc_bt  = (const float*)d_in[32];
    const float* u1_enc_m   = (const float*)d_in[33];
    const float* u1_enc_v   = (const float*)d_in[34];

    float* out = (float*)d_out;
    const size_t OUT0 = 4ull * 64 * 96 * 160;   // 3,932,160
    const size_t OUT1 = 4ull * 64 * 48 * 80;    //   983,040
    const size_t OUT2 = 4ull * 64 * 24 * 40;    //   245,760
    float* out0 = out;
    float* out1 = out + OUT0;
    float* out2 = out + OUT0 + OUT1;

    float* lat0 = (float*)d_ws;
    float* lat1 = lat0 + OUT0;
    float* lat2 = lat1 + OUT1;
    // bf16 weight buffers in d_ws tail (after lat2): ~0.48 MB
    unsigned short* wtb = (unsigned short*)(lat2 + OUT2);
    unsigned short* wt_fpn0 = wtb;
    unsigned short* wt_fpn1 = wtb + 36864;
    unsigned short* wt_fpn2 = wtb + 73728;
    unsigned short* wt_enc0 = wtb + 110592;
    unsigned short* wt_enc1 = wtb + 175104;
    // comp/enc scratch lives in the out0 region (overwritten last by fpn0 conv)
    float* comp = out0;
    float* enc  = out0 + OUT1;

    dim3 blk(256);

    // 0) weight transform (all 5 conv3x3 weight sets -> bf16 [tap][co][ci])
    wt_transform<<<dim3(252, 5), blk, 0, stream>>>(
        fpn0_w, fpn1_w, fpn2_w, u0_enc_w, u1_enc_w, wtb);

    // 1) lateral 1x1 convs + bias
    conv1x1_kernel<128, 4, 0><<<dim3(15, 8, 4), blk, 0, stream>>>(
        x0, lat0_w, lat0_b, nullptr, nullptr, nullptr, lat0, 96 * 160);
    conv1x1_kernel<256, 2, 0><<<dim3(8, 8, 4), blk, 0, stream>>>(
        x1, lat1_w, lat1_b, nullptr, nullptr, nullptr, lat1, 48 * 80);
    conv1x1_kernel<512, 1, 0><<<dim3(4, 8, 4), blk, 0, stream>>>(
        x2, lat2_w, lat2_b, nullptr, nullptr, nullptr, lat2, 24 * 40);

    // 2) CARAFE u1: lat1 += carafe(lat2)
    conv1x1_kernel<64, 1, 1><<<dim3(4, 8, 4), blk, 0, stream>>>(
        lat2, u1_comp_w, u1_comp_g, u1_comp_bt, u1_comp_m, u1_comp_v, comp, 24 * 40);
    conv3x3_mfma<112, 1><<<dim3(3, 2, 4), blk, 0, stream>>>(
        comp, wt_enc1, u1_enc_g, u1_enc_bt, u1_enc_m, u1_enc_v, enc, 24, 40, 100);
    carafe_kernel<16><<<dim3(5, 3, 16), blk, 0, stream>>>(lat2, enc, lat1, 24, 40);

    // 3) CARAFE u0: lat0 += carafe(lat1)
    conv1x1_kernel<64, 1, 1><<<dim3(15, 8, 4), blk, 0, stream>>>(
        lat1, u0_comp_w, u0_comp_g, u0_comp_bt, u0_comp_m, u0_comp_v, comp, 48 * 80);
    conv3x3_mfma<112, 1><<<dim3(5, 3, 4), blk, 0, stream>>>(
        comp, wt_enc0, u0_enc_g, u0_enc_bt, u0_enc_m, u0_enc_v, enc, 48, 80, 100);
    carafe_kernel<16><<<dim3(10, 6, 16), blk, 0, stream>>>(lat1, enc, lat0, 48, 80);

    // 4) output 3x3 convs + bias  (fpn0 LAST — its region held comp/enc scratch)
    conv3x3_mfma<64, 0><<<dim3(5, 3, 4), blk, 0, stream>>>(
        lat1, wt_fpn1, fpn1_b, nullptr, nullptr, nullptr, out1, 48, 80, 64);
    conv3x3_mfma<64, 0><<<dim3(3, 2, 4), blk, 0, stream>>>(
        lat2, wt_fpn2, fpn2_b, nullptr, nullptr, nullptr, out2, 24, 40, 64);
    conv3x3_mfma<64, 0><<<dim3(10, 6, 4), blk, 0, stream>>>(
        lat0, wt_fpn0, fpn0_b, nullptr, nullptr, nullptr, out0, 96, 160, 64);
}

// Round 7
// 581.357 us; speedup vs baseline: 1.8852x; 1.0714x over previous
//
#include <hip/hip_runtime.h>

#define BN_EPS 1e-5f

typedef __attribute__((ext_vector_type(8))) short bf16x8;
typedef __attribute__((ext_vector_type(4))) float f32x4;

__device__ __forceinline__ unsigned short f2bf(float f) {
    unsigned u = __float_as_uint(f);
    return (unsigned short)((u + 0x7fffu + ((u >> 16) & 1u)) >> 16);   // RNE
}

// ---------------------------------------------------------------------------
// Weight transform: w[co][ci][3][3] fp32 -> wt[tap][co_pad][ci] bf16 (zero pad)
// z: 0..2 fpn0/1/2 (co 64->64), 3..4 enc0/1 (co 100->112). grid (252, 5)
// ---------------------------------------------------------------------------
__global__ __launch_bounds__(256)
void wt_transform(const float* __restrict__ w0, const float* __restrict__ w1,
                  const float* __restrict__ w2, const float* __restrict__ w3,
                  const float* __restrict__ w4, unsigned short* __restrict__ dst)
{
    int z = blockIdx.y;
    int i = blockIdx.x * 256 + threadIdx.x;
    const float* src; unsigned short* d; int C_out, COP;
    if (z < 3) {
        COP = 64; C_out = 64;
        src = (z == 0) ? w0 : (z == 1 ? w1 : w2);
        d = dst + z * 36864;
        if (i >= 36864) return;
    } else {
        COP = 112; C_out = 100;
        src = (z == 3) ? w3 : w4;
        d = dst + 110592 + (z - 3) * 64512;
        if (i >= 64512) return;
    }
    int tap = i / (COP * 64);
    int rem = i - tap * (COP * 64);
    int co = rem >> 6, ci = rem & 63;
    float v = (co < C_out) ? src[((size_t)co * 64 + ci) * 9 + tap] : 0.f;
    d[i] = f2bf(v);
}

// ---------------------------------------------------------------------------
// conv3x3 via bf16 MFMA (16x16x32), pad=1, C_in=64, fp32 accumulate.
// (R5 version — known good: MfmaUtil>0, absmax 0.031 < 0.128)
// grid: (ceil(W/16), ceil(H/16), B), block 256
// ---------------------------------------------------------------------------
template<int COP, int MODE>
__global__ __launch_bounds__(256, 4)
void conv3x3_mfma(const float* __restrict__ x, const unsigned short* __restrict__ wt,
                  const float* __restrict__ p0, const float* __restrict__ p1,
                  const float* __restrict__ p2, const float* __restrict__ p3,
                  float* __restrict__ out, int H, int W, int C_out)
{
    constexpr int NP = 324;                      // 18*18 halo pixels
    __shared__ unsigned short xs[8 * NP * 8];    // [cg][p][8ci] bf16, 41472 B

    int tid  = threadIdx.x;
    int lane = tid & 63, wid = tid >> 6;
    int lrow = lane >> 4, lcol = lane & 15;      // lrow = quad
    int x0 = blockIdx.x * 16, y0 = blockIdx.y * 16;
    int b  = blockIdx.z;
    int HWp = H * W;
    const float* xb = x + (size_t)b * 64 * HWp;

    // ---- stage halo tile (fp32 global -> bf16 LDS, transposed to px-major) ----
    unsigned int* wsl = (unsigned int*)xs;
    for (int p = tid; p < NP; p += 256) {
        int py = p / 18, px = p - py * 18;
        int gy = y0 + py - 1, gx = x0 + px - 1;
        bool ok = (gy >= 0) && (gy < H) && (gx >= 0) && (gx < W);
        const float* gp = xb + (size_t)gy * W + gx;
#pragma unroll 4
        for (int cp = 0; cp < 32; ++cp) {        // ci pair
            float v0 = 0.f, v1 = 0.f;
            if (ok) {
                v0 = gp[(size_t)(2 * cp) * HWp];
                v1 = gp[(size_t)(2 * cp + 1) * HWp];
            }
            unsigned pk = ((unsigned)f2bf(v1) << 16) | (unsigned)f2bf(v0);
            wsl[((cp >> 2) * NP + p) * 4 + (cp & 3)] = pk;
        }
    }
    __syncthreads();

    bool colok = (x0 + lcol) < W;

    for (int ct = 0; ct < COP / 16; ++ct) {
        int co0 = ct * 16;

        bf16x8 a[9][2];
        const unsigned short* wl = wt + ((size_t)co0 + lcol) * 64 + lrow * 8;
#pragma unroll
        for (int t = 0; t < 9; ++t)
#pragma unroll
            for (int kb = 0; kb < 2; ++kb)
                a[t][kb] = *(const bf16x8*)(wl + (size_t)t * COP * 64 + kb * 32);

        float sc[4], sh[4];
#pragma unroll
        for (int rg = 0; rg < 4; ++rg) {
            int co = co0 + lrow * 4 + rg;
            int cc = (co < C_out) ? co : 0;
            if (MODE == 0) { sc[rg] = 1.f; sh[rg] = p0[cc]; }
            else {
                float inv = p0[cc] * rsqrtf(p3[cc] + BN_EPS);
                sc[rg] = inv; sh[rg] = p1[cc] - p2[cc] * inv;
            }
        }

#pragma unroll
        for (int rr = 0; rr < 2; ++rr) {
            int r0 = wid + rr * 8;
            f32x4 acc0 = {0.f, 0.f, 0.f, 0.f};
            f32x4 acc1 = {0.f, 0.f, 0.f, 0.f};
#pragma unroll
            for (int t = 0; t < 9; ++t) {
                int dy = t / 3, dx = t - dy * 3;
#pragma unroll
                for (int kb = 0; kb < 2; ++kb) {
                    int g0 = (kb * 4 + lrow) * NP + (r0 + dy) * 18 + lcol + dx;
                    bf16x8 b0 = *(const bf16x8*)(xs + (size_t)g0 * 8);
                    acc0 = __builtin_amdgcn_mfma_f32_16x16x32_bf16(a[t][kb], b0, acc0, 0, 0, 0);
                    bf16x8 b1 = *(const bf16x8*)(xs + ((size_t)g0 + 4 * 18) * 8);
                    acc1 = __builtin_amdgcn_mfma_f32_16x16x32_bf16(a[t][kb], b1, acc1, 0, 0, 0);
                }
            }
            int yA = y0 + r0, yB = y0 + r0 + 4;
#pragma unroll
            for (int rg = 0; rg < 4; ++rg) {
                int co = co0 + lrow * 4 + rg;
                if (colok && co < C_out) {
                    float* oc = out + (((size_t)b * C_out + co) * H) * W + x0 + lcol;
                    if (yA < H) oc[(size_t)yA * W] = acc0[rg] * sc[rg] + sh[rg];
                    if (yB < H) oc[(size_t)yB * W] = acc1[rg] * sc[rg] + sh[rg];
                }
            }
        }
    }
}

// ---------------------------------------------------------------------------
// conv1x1 (R2 version — register-resident, known good)
// MODE 0: + bias (p0)      MODE 1: BN(g,bt,m,v) + ReLU
// grid: (ceil(HW/(256*PIX)), 8, B), block 256
// ---------------------------------------------------------------------------
template<int C_IN, int PIX, int MODE>
__global__ __launch_bounds__(256)
void conv1x1_kernel(const float* __restrict__ x, const float* __restrict__ w,
                    const float* __restrict__ p0, const float* __restrict__ p1,
                    const float* __restrict__ p2, const float* __restrict__ p3,
                    float* __restrict__ out, int HW)
{
    constexpr int CO = 8;
    __shared__ float wl[C_IN][CO];

    int tid = threadIdx.x;
    int co0 = blockIdx.y * CO;
    int b   = blockIdx.z;

    for (int i = tid; i < C_IN * CO; i += 256) {
        int ci = i >> 3, j = i & 7;
        wl[ci][j] = w[(co0 + j) * C_IN + ci];
    }
    __syncthreads();

    int p = (blockIdx.x * 256 + tid) * PIX;
    if (p >= HW) return;

    float acc[CO][PIX];
#pragma unroll
    for (int j = 0; j < CO; ++j)
#pragma unroll
        for (int q = 0; q < PIX; ++q) acc[j][q] = 0.f;

    const float* xp = x + (size_t)b * C_IN * HW + p;

#pragma unroll 8
    for (int ci = 0; ci < C_IN; ++ci) {
        float xv[PIX];
        if (PIX == 4) {
            float4 v = *(const float4*)(xp + (size_t)ci * HW);
            xv[0] = v.x; xv[1] = v.y; xv[2] = v.z; xv[3] = v.w;
        } else if (PIX == 2) {
            float2 v = *(const float2*)(xp + (size_t)ci * HW);
            xv[0] = v.x; xv[1] = v.y;
        } else {
            xv[0] = xp[(size_t)ci * HW];
        }
        float4 wa = *(const float4*)&wl[ci][0];
        float4 wb = *(const float4*)&wl[ci][4];
        float wj[CO] = {wa.x, wa.y, wa.z, wa.w, wb.x, wb.y, wb.z, wb.w};
#pragma unroll
        for (int j = 0; j < CO; ++j)
#pragma unroll
            for (int q = 0; q < PIX; ++q)
                acc[j][q] = fmaf(wj[j], xv[q], acc[j][q]);
    }

    int C_out = gridDim.y * CO;
    float* op = out + ((size_t)(b * C_out + co0)) * HW + p;
#pragma unroll
    for (int j = 0; j < CO; ++j) {
        float scale, shift;
        if (MODE == 0) {
            scale = 1.f; shift = p0[co0 + j];
        } else {
            float inv = p0[co0 + j] * rsqrtf(p3[co0 + j] + BN_EPS);
            scale = inv; shift = p1[co0 + j] - p2[co0 + j] * inv;
        }
        float r[PIX];
#pragma unroll
        for (int q = 0; q < PIX; ++q) {
            r[q] = acc[j][q] * scale + shift;
            if (MODE == 1) r[q] = fmaxf(r[q], 0.f);
        }
        float* od = op + (size_t)j * HW;
        if (PIX == 4)      *(float4*)od = make_float4(r[0], r[1], r[2], r[3]);
        else if (PIX == 2) *(float2*)od = make_float2(r[0], r[1]);
        else               od[0] = r[0];
    }
}

// ---------------------------------------------------------------------------
// CARAFE v3: block = 16x16 output tile, ALL 64 channels.
// v2 was latency-bound (VALUBusy 11%, HBM 10%, 400 scattered global
// loads/thread, 4x redundant logit/src reads across channel-group blocks).
// v3: stage the 12x12 (half-res+halo) x 64ch src patch in LDS ONCE,
// zero-padded (reference zero-pads, softmax over all 25 -> no masking).
// Gathers hit LDS as float4 (16B-aligned: stride 68, pixel base 272B).
// Softmax computed once, reused for all 4 channel passes.
// grid: (2w/16, 2h/16, B), block 256.  Requires 2w%16==0, 2h%16==0.
// ---------------------------------------------------------------------------
__global__ __launch_bounds__(256, 4)
void carafe_kernel(const float* __restrict__ src, const float* __restrict__ logits,
                   float* __restrict__ dst, int h, int w)
{
    constexpr int SW = 12, NPX = 144, CS = 68;   // patch 12x12, ch-stride 68
    __shared__ float ls[NPX * CS];               // 39168 B, pixel-major [p][c]

    int tid = threadIdx.x;
    int x0 = blockIdx.x * 16, y0 = blockIdx.y * 16;
    int b = blockIdx.z;
    int H = 2 * h, W = 2 * w;
    int xs0 = (x0 >> 1) - 2, ys0 = (y0 >> 1) - 2;
    size_t hw = (size_t)h * w;
    const float* sb = src + (size_t)b * 64 * hw;

    // stage zero-padded src patch: ls[p*CS + c]
    for (int i = tid; i < NPX * 64; i += 256) {
        int c = i / NPX, p = i - c * NPX;
        int yy = p / SW, xx = p - yy * SW;
        int sy = ys0 + yy, sx = xs0 + xx;
        float v = 0.f;
        if (sy >= 0 && sy < h && sx >= 0 && sx < w)
            v = sb[(size_t)c * hw + (size_t)sy * w + sx];
        ls[p * CS + c] = v;
    }
    __syncthreads();

    int lx = tid & 15, ty = tid >> 4;
    int x = x0 + lx, y = y0 + ty;
    int xw = x >> 1, yh = y >> 1;
    int par = (y & 1) * 2 + (x & 1);

    const float* lp = logits + ((size_t)(b * 100 + par) * h + yh) * w + xw;
    float l[25];
    float mx = -1e30f;
#pragma unroll
    for (int k = 0; k < 25; ++k) {
        l[k] = lp[(size_t)(4 * k) * hw];
        mx = fmaxf(mx, l[k]);
    }
    float s = 0.f;
#pragma unroll
    for (int k = 0; k < 25; ++k) {
        l[k] = __expf(l[k] - mx);
        s += l[k];
    }
    float invs = 1.f / s;
#pragma unroll
    for (int k = 0; k < 25; ++k) l[k] *= invs;

    // local pixel of tap (ti=0,tj=0): (yh-ys0-2, xw-xs0-2); taps add +ti,+tj
    int pb = (yh - ys0 - 2) * SW + (xw - xs0 - 2);

#pragma unroll 1
    for (int cg = 0; cg < 4; ++cg) {
        float acc[16];
#pragma unroll
        for (int c = 0; c < 16; ++c) acc[c] = 0.f;
#pragma unroll
        for (int k = 0; k < 25; ++k) {
            int ti = k / 5, tj = k - ti * 5;
            const float* q = &ls[(pb + ti * SW + tj) * CS + cg * 16];
            float wk = l[k];
#pragma unroll
            for (int c = 0; c < 16; ++c)
                acc[c] = fmaf(wk, q[c], acc[c]);
        }
        float* dp = dst + (((size_t)(b * 64 + cg * 16)) * H + y) * W + x;
#pragma unroll
        for (int c = 0; c < 16; ++c)
            dp[(size_t)c * H * W] += acc[c];
    }
}

// ---------------------------------------------------------------------------
extern "C" void kernel_launch(void* const* d_in, const int* in_sizes, int n_in,
                              void* d_out, int out_size, void* d_ws, size_t ws_size,
                              hipStream_t stream)
{
    const float* x0      = (const float*)d_in[0];
    const float* lat0_w  = (const float*)d_in[1];
    const float* lat0_b  = (const float*)d_in[2];
    const float* fpn0_w  = (const float*)d_in[3];
    const float* fpn0_b  = (const float*)d_in[4];
    const float* x1      = (const float*)d_in[5];
    const float* lat1_w  = (const float*)d_in[6];
    const float* lat1_b  = (const float*)d_in[7];
    const float* fpn1_w  = (const float*)d_in[8];
    const float* fpn1_b  = (const float*)d_in[9];
    const float* x2      = (const float*)d_in[10];
    const float* lat2_w  = (const float*)d_in[11];
    const float* lat2_b  = (const float*)d_in[12];
    const float* fpn2_w  = (const float*)d_in[13];
    const float* fpn2_b  = (const float*)d_in[14];
    const float* u0_comp_w = (const float*)d_in[15];
    const float* u0_enc_w  = (const float*)d_in[16];
    const float* u0_comp_g  = (const float*)d_in[17];
    const float* u0_comp_bt = (const float*)d_in[18];
    const float* u0_comp_m  = (const float*)d_in[19];
    const float* u0_comp_v  = (const float*)d_in[20];
    const float* u0_enc_g   = (const float*)d_in[21];
    const float* u0_enc_bt  = (const float*)d_in[22];
    const float* u0_enc_m   = (const float*)d_in[23];
    const float* u0_enc_v   = (const float*)d_in[24];
    const float* u1_comp_w = (const float*)d_in[25];
    const float* u1_enc_w  = (const float*)d_in[26];
    const float* u1_comp_g  = (const float*)d_in[27];
    const float* u1_comp_bt = (const float*)d_in[28];
    const float* u1_comp_m  = (const float*)d_in[29];
    const float* u1_comp_v  = (const float*)d_in[30];
    const float* u1_enc_g   = (const float*)d_in[31];
    const float* u1_enc_bt  = (const float*)d_in[32];
    const float* u1_enc_m   = (const float*)d_in[33];
    const float* u1_enc_v   = (const float*)d_in[34];

    float* out = (float*)d_out;
    const size_t OUT0 = 4ull * 64 * 96 * 160;   // 3,932,160
    const size_t OUT1 = 4ull * 64 * 48 * 80;    //   983,040
    const size_t OUT2 = 4ull * 64 * 24 * 40;    //   245,760
    float* out0 = out;
    float* out1 = out + OUT0;
    float* out2 = out + OUT0 + OUT1;

    float* lat0 = (float*)d_ws;
    float* lat1 = lat0 + OUT0;
    float* lat2 = lat1 + OUT1;
    // bf16 weight buffers in d_ws tail (after lat2): ~0.48 MB
    unsigned short* wtb = (unsigned short*)(lat2 + OUT2);
    unsigned short* wt_fpn0 = wtb;
    unsigned short* wt_fpn1 = wtb + 36864;
    unsigned short* wt_fpn2 = wtb + 73728;
    unsigned short* wt_enc0 = wtb + 110592;
    unsigned short* wt_enc1 = wtb + 175104;
    // comp/enc scratch lives in the out0 region (overwritten last by fpn0 conv)
    float* comp = out0;
    float* enc  = out0 + OUT1;

    dim3 blk(256);

    // 0) weight transform (all 5 conv3x3 weight sets -> bf16 [tap][co][ci])
    wt_transform<<<dim3(252, 5), blk, 0, stream>>>(
        fpn0_w, fpn1_w, fpn2_w, u0_enc_w, u1_enc_w, wtb);

    // 1) lateral 1x1 convs + bias
    conv1x1_kernel<128, 4, 0><<<dim3(15, 8, 4), blk, 0, stream>>>(
        x0, lat0_w, lat0_b, nullptr, nullptr, nullptr, lat0, 96 * 160);
    conv1x1_kernel<256, 2, 0><<<dim3(8, 8, 4), blk, 0, stream>>>(
        x1, lat1_w, lat1_b, nullptr, nullptr, nullptr, lat1, 48 * 80);
    conv1x1_kernel<512, 1, 0><<<dim3(4, 8, 4), blk, 0, stream>>>(
        x2, lat2_w, lat2_b, nullptr, nullptr, nullptr, lat2, 24 * 40);

    // 2) CARAFE u1: lat1 += carafe(lat2)
    conv1x1_kernel<64, 1, 1><<<dim3(4, 8, 4), blk, 0, stream>>>(
        lat2, u1_comp_w, u1_comp_g, u1_comp_bt, u1_comp_m, u1_comp_v, comp, 24 * 40);
    conv3x3_mfma<112, 1><<<dim3(3, 2, 4), blk, 0, stream>>>(
        comp, wt_enc1, u1_enc_g, u1_enc_bt, u1_enc_m, u1_enc_v, enc, 24, 40, 100);
    carafe_kernel<<<dim3(5, 3, 4), blk, 0, stream>>>(lat2, enc, lat1, 24, 40);

    // 3) CARAFE u0: lat0 += carafe(lat1)
    conv1x1_kernel<64, 1, 1><<<dim3(15, 8, 4), blk, 0, stream>>>(
        lat1, u0_comp_w, u0_comp_g, u0_comp_bt, u0_comp_m, u0_comp_v, comp, 48 * 80);
    conv3x3_mfma<112, 1><<<dim3(5, 3, 4), blk, 0, stream>>>(
        comp, wt_enc0, u0_enc_g, u0_enc_bt, u0_enc_m, u0_enc_v, enc, 48, 80, 100);
    carafe_kernel<<<dim3(10, 6, 4), blk, 0, stream>>>(lat1, enc, lat0, 48, 80);

    // 4) output 3x3 convs + bias  (fpn0 LAST — its region held comp/enc scratch)
    conv3x3_mfma<64, 0><<<dim3(5, 3, 4), blk, 0, stream>>>(
        lat1, wt_fpn1, fpn1_b, nullptr, nullptr, nullptr, out1, 48, 80, 64);
    conv3x3_mfma<64, 0><<<dim3(3, 2, 4), blk, 0, stream>>>(
        lat2, wt_fpn2, fpn2_b, nullptr, nullptr, nullptr, out2, 24, 40, 64);
    conv3x3_mfma<64, 0><<<dim3(10, 6, 4), blk, 0, stream>>>(
        lat0, wt_fpn0, fpn0_b, nullptr, nullptr, nullptr, out0, 96, 160, 64);
}